// Round 2
// baseline (487.563 us; speedup 1.0000x reference)
//
#include <hip/hip_runtime.h>

#define F 256
#define NODE_BUDGET 200.0f
#define COS_EPS 1e-6f

// Per-root precompute: g[b][f] = x_root*w_ego_root*w_ego_u,
// nrinv[b] = 1/max(||x_root*w_ego_root||, eps), sv[b] = x_root . w_layer_v,
// bscale[b] = budgets[b]/200
__global__ __launch_bounds__(256) void root_kernel(
    const float* __restrict__ x,
    const float* __restrict__ w_ego_root,
    const float* __restrict__ w_ego_u,
    const float* __restrict__ w_layer_v,
    const float* __restrict__ budgets,
    const int* __restrict__ batch_nodes,
    float* __restrict__ g, float* __restrict__ nrinv,
    float* __restrict__ sv, float* __restrict__ bscale)
{
    __shared__ float red[2][4];
    int b = blockIdx.x;
    int f = threadIdx.x;  // F == 256 == blockDim.x
    int root = batch_nodes[b];
    float xf = x[(size_t)root * F + f];
    float hr = xf * w_ego_root[f];
    g[(size_t)b * F + f] = hr * w_ego_u[f];
    float a = hr * hr;
    float c = xf * w_layer_v[f];
    #pragma unroll
    for (int off = 32; off; off >>= 1) {
        a += __shfl_xor(a, off);
        c += __shfl_xor(c, off);
    }
    int lane = f & 63, wv = f >> 6;
    if (lane == 0) { red[0][wv] = a; red[1][wv] = c; }
    __syncthreads();
    if (f == 0) {
        float as = red[0][0] + red[0][1] + red[0][2] + red[0][3];
        float cs = red[1][0] + red[1][1] + red[1][2] + red[1][3];
        nrinv[b] = 1.0f / fmaxf(sqrtf(as), COS_EPS);
        sv[b] = cs;
        bscale[b] = budgets[b] * (1.0f / NODE_BUDGET);
    }
}

// Build per-node candidate linked lists: head[u] -> chain of m via next[m].
// atomicExch order is nondeterministic but per-m outputs are order-independent.
__global__ __launch_bounds__(256) void build_lists_kernel(
    const int* __restrict__ u_ids, int* __restrict__ head,
    int* __restrict__ next, int M)
{
    int i = blockIdx.x * 256 + threadIdx.x;
    if (i >= M) return;
    int u = u_ids[i];
    next[i] = atomicExch(&head[u], i);
}

// agg[dst] += sv[src] over E edges (dst ~uniform over M=500k -> low contention)
__global__ __launch_bounds__(256) void edge_kernel(
    const int* __restrict__ edge_src, const int* __restrict__ edge_dst,
    const float* __restrict__ sv, float* __restrict__ agg, int E)
{
    int i = blockIdx.x * 256 + threadIdx.x;
    int stride = gridDim.x * 256;
    for (; i < E; i += stride)
        atomicAdd(&agg[edge_dst[i]], sv[edge_src[i]]);
}

// One 16-lane group per NODE: x row loaded into registers ONCE, u-only terms
// (||x*w_ego_u||, x.w_layer_u) computed ONCE, then walk the candidate list.
// x traffic drops 500MB -> ~184MB compulsory; per-element g gathers are random
// but g is 1MB total -> L2-resident on every XCD.
__global__ __launch_bounds__(256) void cand_list_kernel(
    const float* __restrict__ x,
    const int* __restrict__ head, const int* __restrict__ next,
    const int* __restrict__ batch_ptr,
    const float* __restrict__ g, const float* __restrict__ nrinv,
    const float* __restrict__ bscale, const float* __restrict__ agg,
    const float* __restrict__ w_ego_u, const float* __restrict__ w_layer_u,
    const float* __restrict__ n_imp,
    float* __restrict__ p_out, int N)
{
    int tid = threadIdx.x;
    int lane = tid & 63;
    int sub = lane >> 4;          // which of 4 nodes in this wave
    int sl = lane & 15;           // sub-lane within node group
    int n = blockIdx.x * 16 + (tid >> 6) * 4 + sub;
    if (n >= N) return;
    int m = head[n];
    if (m < 0) return;            // node has no candidates

    const float4* xr  = (const float4*)(x + (size_t)n * F);
    const float4* weu = (const float4*)w_ego_u;     // 1KB, L1-broadcast
    const float4* wlu = (const float4*)w_layer_u;   // 1KB, L1-broadcast

    float4 xv0 = xr[sl], xv1 = xr[16 + sl], xv2 = xr[32 + sl], xv3 = xr[48 + sl];
    float a2 = 0.0f, su = 0.0f;
    {
        float4 wu, wl, xv;
        #define ACCUM(XV, P) \
            xv = XV; wu = weu[(P)*16 + sl]; wl = wlu[(P)*16 + sl]; \
            { float h0 = xv.x*wu.x, h1 = xv.y*wu.y, h2 = xv.z*wu.z, h3 = xv.w*wu.w; \
              a2 += h0*h0 + h1*h1 + h2*h2 + h3*h3; \
              su += xv.x*wl.x + xv.y*wl.y + xv.z*wl.z + xv.w*wl.w; }
        ACCUM(xv0, 0) ACCUM(xv1, 1) ACCUM(xv2, 2) ACCUM(xv3, 3)
        #undef ACCUM
    }
    #pragma unroll
    for (int off = 8; off; off >>= 1) {
        a2 += __shfl_xor(a2, off);
        su += __shfl_xor(su, off);
    }
    float inv_nu = 1.0f / fmaxf(sqrtf(a2), COS_EPS);
    float imp = n_imp[n];

    while (m >= 0) {
        int mn = next[m];                 // issue chase early
        int b = batch_ptr[m];
        float ag = agg[m];
        const float4* gr = (const float4*)(g + (size_t)b * F);   // L2-resident
        float4 g0 = gr[sl], g1 = gr[16 + sl], g2 = gr[32 + sl], g3 = gr[48 + sl];
        float acc = xv0.x*g0.x + xv0.y*g0.y + xv0.z*g0.z + xv0.w*g0.w
                  + xv1.x*g1.x + xv1.y*g1.y + xv1.z*g1.z + xv1.w*g1.w
                  + xv2.x*g2.x + xv2.y*g2.y + xv2.z*g2.z + xv2.w*g2.w
                  + xv3.x*g3.x + xv3.y*g3.y + xv3.z*g3.z + xv3.w*g3.w;
        #pragma unroll
        for (int off = 8; off; off >>= 1)
            acc += __shfl_xor(acc, off);
        if (sl == 0) {
            float ego = acc * inv_nu * nrinv[b];
            float layer = tanhf(ag + su);
            p_out[m] = (0.5f * ego + 0.5f * layer) * imp * bscale[b];
        }
        m = mn;
    }
}

// Fused segment-max + normalize: batch_ptr sorted -> contiguous segments.
// One block per b; binary-search bounds; max-reduce; normalize in place.
__global__ __launch_bounds__(256) void seg_norm_kernel(
    const int* __restrict__ batch_ptr, float* __restrict__ out, int M)
{
    int b = blockIdx.x;
    int lo = 0, hi = M;
    while (lo < hi) { int mid = (lo + hi) >> 1; if (batch_ptr[mid] < b) lo = mid + 1; else hi = mid; }
    int start = lo;
    hi = M;
    while (lo < hi) { int mid = (lo + hi) >> 1; if (batch_ptr[mid] <= b) lo = mid + 1; else hi = mid; }
    int end = lo;
    float mx = -INFINITY;
    for (int i = start + threadIdx.x; i < end; i += 256)
        mx = fmaxf(mx, out[i]);
    #pragma unroll
    for (int off = 32; off; off >>= 1)
        mx = fmaxf(mx, __shfl_xor(mx, off));
    __shared__ float red[4];
    __shared__ float s_pn;
    int lane = threadIdx.x & 63, wv = threadIdx.x >> 6;
    if (lane == 0) red[wv] = mx;
    __syncthreads();
    if (threadIdx.x == 0)
        s_pn = fmaxf(fmaxf(red[0], red[1]), fmaxf(red[2], red[3]));
    __syncthreads();
    float pn = s_pn;
    for (int i = start + threadIdx.x; i < end; i += 256) {
        float v = out[i] / pn + 1.0f;
        if (isnan(v)) v = 0.0f;
        else if (isinf(v)) v = 1.0f;
        out[i] = fminf(fmaxf(v, 1e-5f), 1.0f);
    }
}

extern "C" void kernel_launch(void* const* d_in, const int* in_sizes, int n_in,
                              void* d_out, int out_size, void* d_ws, size_t ws_size,
                              hipStream_t stream) {
    const float* x          = (const float*)d_in[0];
    const float* w_ego_root = (const float*)d_in[1];
    const float* w_ego_u    = (const float*)d_in[2];
    const float* w_layer_v  = (const float*)d_in[3];
    const float* w_layer_u  = (const float*)d_in[4];
    const float* n_imp      = (const float*)d_in[5];
    const float* budgets    = (const float*)d_in[6];
    const int* batch_nodes = (const int*)d_in[7];
    const int* u_ids       = (const int*)d_in[8];
    const int* batch_ptr   = (const int*)d_in[9];
    const int* edge_src    = (const int*)d_in[10];
    const int* edge_dst    = (const int*)d_in[11];
    float* out = (float*)d_out;

    int N = in_sizes[5];
    int B = in_sizes[7];
    int M = in_sizes[8];
    int E = in_sizes[10];

    float* ws = (float*)d_ws;
    size_t off = 0;
    float* agg = ws + off;                          off += (size_t)((M + 3) & ~3);
    size_t zero_bytes = off * sizeof(float);        // agg needs zero-init
    float* g       = ws + off;                      off += (size_t)B * F;
    float* nrinv   = ws + off;                      off += (size_t)((B + 3) & ~3);
    float* sv      = ws + off;                      off += (size_t)((B + 3) & ~3);
    float* bscale  = ws + off;                      off += (size_t)((B + 3) & ~3);
    int* head      = (int*)(ws + off);              off += (size_t)((N + 3) & ~3);
    int* next      = (int*)(ws + off);              off += (size_t)((M + 3) & ~3);

    hipMemsetAsync(d_ws, 0, zero_bytes, stream);
    hipMemsetAsync(head, 0xFF, (size_t)N * sizeof(int), stream);  // head = -1

    root_kernel<<<B, 256, 0, stream>>>(x, w_ego_root, w_ego_u, w_layer_v,
                                       budgets, batch_nodes, g, nrinv, sv, bscale);
    build_lists_kernel<<<(M + 255) / 256, 256, 0, stream>>>(u_ids, head, next, M);
    edge_kernel<<<2048, 256, 0, stream>>>(edge_src, edge_dst, sv, agg, E);
    cand_list_kernel<<<(N + 15) / 16, 256, 0, stream>>>(x, head, next, batch_ptr,
                                                        g, nrinv, bscale, agg,
                                                        w_ego_u, w_layer_u, n_imp,
                                                        out, N);
    seg_norm_kernel<<<B, 256, 0, stream>>>(batch_ptr, out, M);
}